// Round 10
// baseline (587.026 us; speedup 1.0000x reference)
//
#include <hip/hip_runtime.h>

// Problem constants (fixed by setup_inputs)
#define BQ   16
#define HH   512
#define WW   512
#define CC   3
#define PSZ  16
#define STR  8
#define PYN  63
#define PXN  63
#define NPATCH (BQ * PYN * PXN)   // 63504
#define HID  512
#define MT   24                   // patches per block; 63504/24 = 2646 exactly
#define NTH  1024                 // 16 waves: each owns a 32-col N slice, 2 M-tiles
#define KSTEPS 48                 // 1536 / 32
#define M1BASE 24576              // ushort offset of the 8-patch M1 region

typedef __attribute__((ext_vector_type(8))) short  short8;
typedef __attribute__((ext_vector_type(4))) float  f32x4;

__device__ __forceinline__ ushort f2bf(float f) {
    unsigned u = __float_as_uint(f);
    u = (u + 0x7fffu + ((u >> 16) & 1u)) >> 16;   // RNE
    return (ushort)u;
}
__device__ __forceinline__ float bf2f(ushort h) {
    return __uint_as_float(((unsigned)h) << 16);
}
__device__ __forceinline__ unsigned pk2(float a, float b) {
    return (unsigned)f2bf(a) | ((unsigned)f2bf(b) << 16);
}

// feat addressing with sigma-swizzle (slot = patch ^ (kblock & mask)):
//  pi<16 : (B<<7) + ((pi ^ (B&15))<<3) + kk          B=k>>3, kk=k&7
//  pi>=16: M1BASE + (B<<6) + (((pi-16)^(B&7))<<3) + kk
__device__ __forceinline__ int fidx(int pi, int k) {
    int B = k >> 3, kk = k & 7;
    if (pi < 16) return (B << 7) + ((pi ^ (B & 15)) << 3) + kk;
    return M1BASE + (B << 6) + (((pi - 16) ^ (B & 7)) << 3) + kk;
}

// Pack w1[0:1536][0:512] -> bf16, lane-linear fragment order (unchanged from R9):
// idx = ((s*32 + ntg)*64 + g*16 + cn)*8 + kk
__global__ void pack_w1_kernel(const float* __restrict__ w1, ushort* __restrict__ w1p) {
    int e = blockIdx.x * 256 + threadIdx.x;   // 0 .. 1536*512-1
    int k = e >> 9;
    int n = e & 511;
    int idx = ((k >> 5) << 14) + ((n >> 4) << 9) + (((k >> 3) & 3) << 7) + ((n & 15) << 3) + (k & 7);
    w1p[idx] = f2bf(w1[e]);
}

__global__ __launch_bounds__(NTH, 8)
void lfe_mfma_kernel(const float* __restrict__ img1,
                     const float* __restrict__ img2,
                     const float* __restrict__ prior,
                     const float* __restrict__ w1,
                     const float* __restrict__ b1,
                     const float* __restrict__ w2,
                     const float* __restrict__ b2,
                     const ushort* __restrict__ w1p,
                     float* __restrict__ out)
{
    __shared__ ushort feat[36864];            // 73728 B : M0 (16 patches) + M1 (8 patches)
    __shared__ float  red[16][MT][2];         // 6144 B
    __shared__ float  srem[MT][2];
    __shared__ float  sflow[MT][2];
    __shared__ int    sip[MT][2];
    __shared__ int    sbase1[MT];
    __shared__ int    sbase2[MT];
    // total ~80.6 KB -> 2 blocks/CU

    const int t    = threadIdx.x;
    const int wid  = t >> 6;         // 0..15
    const int lane = t & 63;
    const int n0   = blockIdx.x * MT;

    // ---- Hoisted B prefetch (independent of LDS; hides under phases 0-1) ----
    const int ntb = wid << 1;                      // first ntg of this wave's 32-col slice
    const ushort* bbase = w1p + ((size_t)lane << 3);
    short8 B0[2], B1[2];
    #define LOADB(Bv, s_) {                                           \
        const ushort* p_ = bbase + ((size_t)(((s_) << 5) + ntb) << 9);\
        Bv[0] = *(const short8*)(p_);                                 \
        Bv[1] = *(const short8*)(p_ + 512);                           \
    }
    LOADB(B0, 0);
    LOADB(B1, 1);

    // ---- Phase 0: prior -> int/remainder + patch base offsets ----
    if (t < MT) {
        int n = n0 + t;
        float py_ = prior[(size_t)n * 2 + 0];
        float px_ = prior[(size_t)n * 2 + 1];
        int ipy = (int)rintf(py_);   // RNE == jnp.round
        int ipx = (int)rintf(px_);
        sip[t][0] = ipy; sip[t][1] = ipx;
        srem[t][0] = py_ - (float)ipy;
        srem[t][1] = px_ - (float)ipx;
        int b  = n / (PYN * PXN);
        int r  = n % (PYN * PXN);
        int py = r / PXN, px = r % PXN;
        int by = py * STR, bx = px * STR;
        int sy = min(max(by + ipy, 0), HH - PSZ);
        int sx = min(max(bx + ipx, 0), WW - PSZ);
        sbase1[t] = ((b * HH + by) * WW + bx) * CC;
        sbase2[t] = ((b * HH + sy) * WW + sx) * CC;
    }
    __syncthreads();

    // ---- Phase 1: stage patches (bf16) in swizzled fragment order ----
    // combos c=0..383: c<192 -> M0 (16 patches, all lanes), else M1 (8 patches, plo<8).
    {
        const int plo = lane >> 2;
        const int kk2 = lane & 3;
        #pragma unroll 4
        for (int i = 0; i < 24; ++i) {
            int c  = (i << 4) + wid;          // 0..383, wave-uniform
            int m1 = (c >= 192);
            int r  = c - (m1 ? 192 : 0);
            int s  = r >> 2, g = r & 3;
            int Bb = (s << 2) + g;
            bool active = true;
            int pi, idx;
            if (!m1) {
                pi  = plo;
                idx = (s << 9) + (g << 7) + (((plo) ^ (Bb & 15)) << 3) + (kk2 << 1);
            } else {
                active = (plo < 8);
                pi  = 16 + (plo & 7);
                idx = M1BASE + (s << 8) + (g << 6) + ((((plo) & 7) ^ (Bb & 7)) << 3) + (kk2 << 1);
            }
            if (active) {
                int ka = (s << 5) + (g << 3) + (kk2 << 1);   // absolute k (even)
                const float* src;
                int e;
                if (ka < 768) { src = img1 + sbase1[pi]; e = ka; }
                else          { src = img2 + sbase2[pi]; e = ka - 768; }
                int yi  = e / 48;                 // 8-runs never straddle 48-boundaries
                int off = e - yi * 48;
                const float* g8 = src + yi * (WW * CC) + off;
                *(unsigned*)(&feat[idx]) = pk2(g8[0], g8[1]);
            }
        }
    }
    __syncthreads();

    // ---- Phase 2: MFMA GEMM, B in registers, prefetch distance 2, NO barriers ----
    const int cn = lane & 15;
    const int g  = lane >> 4;

    f32x4 acc[2][2];
    #pragma unroll
    for (int m = 0; m < 2; ++m)
        #pragma unroll
        for (int nt = 0; nt < 2; ++nt) acc[m][nt] = f32x4{0.f, 0.f, 0.f, 0.f};

    for (int s = 0; s < KSTEPS; s += 2) {
        {
            int Bb = (s << 2) + g;
            short8 A0 = *(const short8*)(feat + (s << 9) + (g << 7) + ((cn ^ (Bb & 15)) << 3));
            short8 A1 = *(const short8*)(feat + M1BASE + (s << 8) + (g << 6) + (((lane & 7) ^ (Bb & 7)) << 3));
            #pragma unroll
            for (int nt = 0; nt < 2; ++nt) {
                acc[0][nt] = __builtin_amdgcn_mfma_f32_16x16x32_bf16(A0, B0[nt], acc[0][nt], 0, 0, 0);
                acc[1][nt] = __builtin_amdgcn_mfma_f32_16x16x32_bf16(A1, B0[nt], acc[1][nt], 0, 0, 0);
            }
        }
        int sa = (s + 2 < KSTEPS) ? s + 2 : KSTEPS - 1;   // clamped dummy at tail
        LOADB(B0, sa);
        {
            int s1 = s + 1;
            int Bb = (s1 << 2) + g;
            short8 A0 = *(const short8*)(feat + (s1 << 9) + (g << 7) + ((cn ^ (Bb & 15)) << 3));
            short8 A1 = *(const short8*)(feat + M1BASE + (s1 << 8) + (g << 6) + (((lane & 7) ^ (Bb & 7)) << 3));
            #pragma unroll
            for (int nt = 0; nt < 2; ++nt) {
                acc[0][nt] = __builtin_amdgcn_mfma_f32_16x16x32_bf16(A0, B1[nt], acc[0][nt], 0, 0, 0);
                acc[1][nt] = __builtin_amdgcn_mfma_f32_16x16x32_bf16(A1, B1[nt], acc[1][nt], 0, 0, 0);
            }
        }
        int sb = (s + 3 < KSTEPS) ? s + 3 : KSTEPS - 1;
        LOADB(B1, sb);
    }
    #undef LOADB

    // ---- Phase 3: epilogue — rem features + b1, ReLU, fold w2, reduce over cn ----
    float ps[2][4][2];
    #pragma unroll
    for (int m = 0; m < 2; ++m)
        #pragma unroll
        for (int r = 0; r < 4; ++r) { ps[m][r][0] = 0.f; ps[m][r][1] = 0.f; }

    #pragma unroll
    for (int nt = 0; nt < 2; ++nt) {
        int j = (wid << 5) + (nt << 4) + cn;
        float w1a = w1[(size_t)1536 * HID + j];
        float w1b = w1[(size_t)1537 * HID + j];
        float bb  = b1[j];
        float w20 = w2[(size_t)j * 2 + 0];
        float w21 = w2[(size_t)j * 2 + 1];
        #pragma unroll
        for (int m = 0; m < 2; ++m) {
            #pragma unroll
            for (int r = 0; r < 4; ++r) {
                int pr = (m << 4) + (g << 2) + r;   // C/D: row = (lane>>4)*4 + reg
                if (pr < MT) {
                    float h = acc[m][nt][r] + bb + srem[pr][0] * w1a + srem[pr][1] * w1b;
                    h = fmaxf(h, 0.f);
                    ps[m][r][0] = fmaf(h, w20, ps[m][r][0]);
                    ps[m][r][1] = fmaf(h, w21, ps[m][r][1]);
                }
            }
        }
    }
    #pragma unroll
    for (int m = 0; m < 2; ++m)
        #pragma unroll
        for (int r = 0; r < 4; ++r)
            #pragma unroll
            for (int cc = 0; cc < 2; ++cc)
                #pragma unroll
                for (int off = 1; off < 16; off <<= 1)
                    ps[m][r][cc] += __shfl_xor(ps[m][r][cc], off, 64);
    if (cn == 0) {
        #pragma unroll
        for (int m = 0; m < 2; ++m)
            #pragma unroll
            for (int r = 0; r < 4; ++r) {
                int pr = (m << 4) + (g << 2) + r;
                if (pr < MT) {
                    red[wid][pr][0] = ps[m][r][0];
                    red[wid][pr][1] = ps[m][r][1];
                }
            }
    }
    __syncthreads();
    if (t < MT * 2) {
        int pr = t >> 1, c = t & 1;
        float v = b2[c];
        #pragma unroll
        for (int w = 0; w < 16; ++w) v += red[w][pr][c];
        sflow[pr][c] = srem[pr][c] + v;   // remainder_flow
    }
    __syncthreads();

    // ---- Phase 4: bilinear warp loss, 32 lanes per patch (xj = lt&15, y-half = lt>>4) ----
    {
        const int gi = t >> 5;        // 0..31
        const int lt = t & 31;
        if (gi < MT) {
            const int pi = gi;
            const float rfy = sflow[pi][0], rfx = sflow[pi][1];
            const int xj = lt & 15;
            const int yh = lt >> 4;

            float x  = (float)xj + rfx;
            int   x0 = min(max((int)floorf(x), 0), PSZ - 1);
            int   x1 = min(x0 + 1, PSZ - 1);
            float wx = fminf(fmaxf(x - (float)x0, 0.f), 1.f);
            int   c0 = x0 * 3, c1 = x1 * 3;

            float lsum = 0.f;
            #pragma unroll
            for (int yy = 0; yy < 8; ++yy) {
                int yi = (yh << 3) + yy;
                float y  = (float)yi + rfy;
                int   y0 = min(max((int)floorf(y), 0), PSZ - 1);
                int   y1 = min(y0 + 1, PSZ - 1);
                float wy = fminf(fmaxf(y - (float)y0, 0.f), 1.f);
                int r0 = 768 + y0 * 48, r1 = 768 + y1 * 48;
                int ep = yi * 48 + xj * 3;
                #pragma unroll
                for (int cc = 0; cc < 3; ++cc) {
                    float v00 = bf2f(feat[fidx(pi, r0 + c0 + cc)]);
                    float v01 = bf2f(feat[fidx(pi, r0 + c1 + cc)]);
                    float v10 = bf2f(feat[fidx(pi, r1 + c0 + cc)]);
                    float v11 = bf2f(feat[fidx(pi, r1 + c1 + cc)]);
                    float a = v00 + wx * (v01 - v00);
                    float b = v10 + wx * (v11 - v10);
                    float warped = a + wy * (b - a);
                    float d = warped - bf2f(feat[fidx(pi, ep + cc)]);
                    lsum = fmaf(d, d, lsum);
                }
            }
            #pragma unroll
            for (int off = 1; off < 32; off <<= 1)
                lsum += __shfl_xor(lsum, off, 64);

            if (lt == 0) {
                int n = n0 + pi;
                out[(size_t)n * 3 + 0] = (float)sip[pi][0] + rfy;
                out[(size_t)n * 3 + 1] = (float)sip[pi][1] + rfx;
                out[(size_t)n * 3 + 2] = lsum * (1.f / 768.f);
            }
        }
    }
}

extern "C" void kernel_launch(void* const* d_in, const int* in_sizes, int n_in,
                              void* d_out, int out_size, void* d_ws, size_t ws_size,
                              hipStream_t stream) {
    const float* img1  = (const float*)d_in[0];
    const float* img2  = (const float*)d_in[1];
    const float* prior = (const float*)d_in[2];
    const float* w1    = (const float*)d_in[3];
    const float* b1    = (const float*)d_in[4];
    const float* w2    = (const float*)d_in[5];
    const float* b2    = (const float*)d_in[6];
    float* out = (float*)d_out;
    ushort* w1p = (ushort*)d_ws;            // 1536*512*2 B = 1.57 MB

    pack_w1_kernel<<<dim3((1536 * HID) / 256), dim3(256), 0, stream>>>(w1, w1p);

    dim3 grid(NPATCH / MT);                 // 2646 blocks, exact
    dim3 block(NTH);
    lfe_mfma_kernel<<<grid, block, 0, stream>>>(img1, img2, prior, w1, b1, w2, b2, w1p, out);
}

// Round 11
// 477.974 us; speedup vs baseline: 1.2282x; 1.2282x over previous
//
#include <hip/hip_runtime.h>

// Problem constants (fixed by setup_inputs)
#define BQ   16
#define HH   512
#define WW   512
#define CC   3
#define PSZ  16
#define STR  8
#define PYN  63
#define PXN  63
#define NPATCH (BQ * PYN * PXN)   // 63504
#define HID  512
#define MT   24                   // patches per block; 63504/24 = 2646 exactly
#define NTH  512                  // 8 waves: each owns a 64-col N slice, 2 M-tiles (16+8)
#define KSTEPS 48                 // 1536 / 32
#define M1BASE 24576              // ushort offset of the 8-patch M1 region

typedef __attribute__((ext_vector_type(8))) short  short8;
typedef __attribute__((ext_vector_type(4))) float  f32x4;

__device__ __forceinline__ ushort f2bf(float f) {
    unsigned u = __float_as_uint(f);
    u = (u + 0x7fffu + ((u >> 16) & 1u)) >> 16;   // RNE
    return (ushort)u;
}
__device__ __forceinline__ float bf2f(ushort h) {
    return __uint_as_float(((unsigned)h) << 16);
}
__device__ __forceinline__ unsigned pk2(float a, float b) {
    return (unsigned)f2bf(a) | ((unsigned)f2bf(b) << 16);
}

// feat addressing with sigma-swizzle (slot = patch ^ (kblock & mask)):
//  pi<16 : (B<<7) + ((pi ^ (B&15))<<3) + kk          B=k>>3, kk=k&7
//  pi>=16: M1BASE + (B<<6) + (((pi-16)^(B&7))<<3) + kk
__device__ __forceinline__ int fidx(int pi, int k) {
    int B = k >> 3, kk = k & 7;
    if (pi < 16) return (B << 7) + ((pi ^ (B & 15)) << 3) + kk;
    return M1BASE + (B << 6) + (((pi - 16) ^ (B & 7)) << 3) + kk;
}

// Pack w1[0:1536][0:512] -> bf16, lane-linear fragment order:
// idx = ((s*32 + ntg)*64 + g*16 + cn)*8 + kk
__global__ void pack_w1_kernel(const float* __restrict__ w1, ushort* __restrict__ w1p) {
    int e = blockIdx.x * 256 + threadIdx.x;   // 0 .. 1536*512-1
    int k = e >> 9;
    int n = e & 511;
    int idx = ((k >> 5) << 14) + ((n >> 4) << 9) + (((k >> 3) & 3) << 7) + ((n & 15) << 3) + (k & 7);
    w1p[idx] = f2bf(w1[e]);
}

__global__ __launch_bounds__(NTH, 4)   // 4 waves/SIMD -> VGPR cap 128, 2 blocks/CU via LDS
void lfe_mfma_kernel(const float* __restrict__ img1,
                     const float* __restrict__ img2,
                     const float* __restrict__ prior,
                     const float* __restrict__ w1,
                     const float* __restrict__ b1,
                     const float* __restrict__ w2,
                     const float* __restrict__ b2,
                     const ushort* __restrict__ w1p,
                     float* __restrict__ out)
{
    __shared__ ushort feat[36864];            // 73728 B : M0 (16 patches) + M1 (8 patches)
    __shared__ float  red[8][MT][2];          // 1536 B
    __shared__ float  srem[MT][2];
    __shared__ float  sflow[MT][2];
    __shared__ int    sip[MT][2];
    __shared__ int    sbase1[MT];
    __shared__ int    sbase2[MT];
    // total ~76 KB -> 2 blocks/CU

    const int t    = threadIdx.x;
    const int wid  = t >> 6;         // 0..7
    const int lane = t & 63;
    const int n0   = blockIdx.x * MT;

    // ---- Hoisted B prefetch (independent of LDS; hides under phases 0-1) ----
    const int ntb = wid << 2;                      // first ntg of this wave's 64-col slice
    const ushort* bbase = w1p + ((size_t)lane << 3);
    short8 B0[4], B1[4];
    #define LOADB(Bv, s_) {                                           \
        const ushort* p_ = bbase + ((size_t)(((s_) << 5) + ntb) << 9);\
        Bv[0] = *(const short8*)(p_);                                 \
        Bv[1] = *(const short8*)(p_ + 512);                           \
        Bv[2] = *(const short8*)(p_ + 1024);                          \
        Bv[3] = *(const short8*)(p_ + 1536);                          \
    }
    LOADB(B0, 0);
    LOADB(B1, 1);

    // ---- Phase 0: prior -> int/remainder + patch base offsets ----
    if (t < MT) {
        int n = n0 + t;
        float py_ = prior[(size_t)n * 2 + 0];
        float px_ = prior[(size_t)n * 2 + 1];
        int ipy = (int)rintf(py_);   // RNE == jnp.round
        int ipx = (int)rintf(px_);
        sip[t][0] = ipy; sip[t][1] = ipx;
        srem[t][0] = py_ - (float)ipy;
        srem[t][1] = px_ - (float)ipx;
        int b  = n / (PYN * PXN);
        int r  = n % (PYN * PXN);
        int py = r / PXN, px = r % PXN;
        int by = py * STR, bx = px * STR;
        int sy = min(max(by + ipy, 0), HH - PSZ);
        int sx = min(max(bx + ipx, 0), WW - PSZ);
        sbase1[t] = ((b * HH + by) * WW + bx) * CC;
        sbase2[t] = ((b * HH + sy) * WW + sx) * CC;
    }
    __syncthreads();

    // ---- Phase 1: stage patches (bf16) in swizzled fragment order ----
    // combos c=0..383: c<192 -> M0 (16 patches, all lanes), else M1 (8 patches, plo<8).
    {
        const int plo = lane >> 2;
        const int kk2 = lane & 3;
        #pragma unroll 4
        for (int i = 0; i < 48; ++i) {
            int c  = (i << 3) + wid;          // 0..383, wave-uniform
            int m1 = (c >= 192);
            int r  = c - (m1 ? 192 : 0);
            int s  = r >> 2, g = r & 3;
            int Bb = (s << 2) + g;
            bool active = true;
            int pi, idx;
            if (!m1) {
                pi  = plo;
                idx = (s << 9) + (g << 7) + ((plo ^ (Bb & 15)) << 3) + (kk2 << 1);
            } else {
                active = (plo < 8);
                pi  = 16 + (plo & 7);
                idx = M1BASE + (s << 8) + (g << 6) + (((plo & 7) ^ (Bb & 7)) << 3) + (kk2 << 1);
            }
            if (active) {
                int ka = (s << 5) + (g << 3) + (kk2 << 1);   // absolute k (even)
                const float* src;
                int e;
                if (ka < 768) { src = img1 + sbase1[pi]; e = ka; }
                else          { src = img2 + sbase2[pi]; e = ka - 768; }
                int yi  = e / 48;                 // 8-runs never straddle 48-boundaries
                int off = e - yi * 48;
                const float* g8 = src + yi * (WW * CC) + off;
                *(unsigned*)(&feat[idx]) = pk2(g8[0], g8[1]);
            }
        }
    }
    __syncthreads();

    // ---- Phase 2: MFMA GEMM, B in registers, prefetch distance 2, NO barriers ----
    const int cn = lane & 15;
    const int g  = lane >> 4;

    f32x4 acc[2][4];
    #pragma unroll
    for (int m = 0; m < 2; ++m)
        #pragma unroll
        for (int nt = 0; nt < 4; ++nt) acc[m][nt] = f32x4{0.f, 0.f, 0.f, 0.f};

    for (int s = 0; s < KSTEPS; s += 2) {
        {
            int Bb = (s << 2) + g;
            short8 A0 = *(const short8*)(feat + (s << 9) + (g << 7) + ((cn ^ (Bb & 15)) << 3));
            short8 A1 = *(const short8*)(feat + M1BASE + (s << 8) + (g << 6) + (((lane & 7) ^ (Bb & 7)) << 3));
            #pragma unroll
            for (int nt = 0; nt < 4; ++nt) {
                acc[0][nt] = __builtin_amdgcn_mfma_f32_16x16x32_bf16(A0, B0[nt], acc[0][nt], 0, 0, 0);
                acc[1][nt] = __builtin_amdgcn_mfma_f32_16x16x32_bf16(A1, B0[nt], acc[1][nt], 0, 0, 0);
            }
        }
        int sa = (s + 2 < KSTEPS) ? s + 2 : KSTEPS - 1;   // clamped dummy at tail
        LOADB(B0, sa);
        {
            int s1 = s + 1;
            int Bb = (s1 << 2) + g;
            short8 A0 = *(const short8*)(feat + (s1 << 9) + (g << 7) + ((cn ^ (Bb & 15)) << 3));
            short8 A1 = *(const short8*)(feat + M1BASE + (s1 << 8) + (g << 6) + (((lane & 7) ^ (Bb & 7)) << 3));
            #pragma unroll
            for (int nt = 0; nt < 4; ++nt) {
                acc[0][nt] = __builtin_amdgcn_mfma_f32_16x16x32_bf16(A0, B1[nt], acc[0][nt], 0, 0, 0);
                acc[1][nt] = __builtin_amdgcn_mfma_f32_16x16x32_bf16(A1, B1[nt], acc[1][nt], 0, 0, 0);
            }
        }
        int sb = (s + 3 < KSTEPS) ? s + 3 : KSTEPS - 1;
        LOADB(B1, sb);
    }
    #undef LOADB

    // ---- Phase 3: epilogue — rem features + b1, ReLU, fold w2, reduce over cn ----
    float ps[2][4][2];
    #pragma unroll
    for (int m = 0; m < 2; ++m)
        #pragma unroll
        for (int r = 0; r < 4; ++r) { ps[m][r][0] = 0.f; ps[m][r][1] = 0.f; }

    #pragma unroll
    for (int nt = 0; nt < 4; ++nt) {
        int j = (wid << 6) + (nt << 4) + cn;
        float w1a = w1[(size_t)1536 * HID + j];
        float w1b = w1[(size_t)1537 * HID + j];
        float bb  = b1[j];
        float w20 = w2[(size_t)j * 2 + 0];
        float w21 = w2[(size_t)j * 2 + 1];
        #pragma unroll
        for (int m = 0; m < 2; ++m) {
            #pragma unroll
            for (int r = 0; r < 4; ++r) {
                int pr = (m << 4) + (g << 2) + r;   // C/D: row = (lane>>4)*4 + reg
                if (pr < MT) {
                    float h = acc[m][nt][r] + bb + srem[pr][0] * w1a + srem[pr][1] * w1b;
                    h = fmaxf(h, 0.f);
                    ps[m][r][0] = fmaf(h, w20, ps[m][r][0]);
                    ps[m][r][1] = fmaf(h, w21, ps[m][r][1]);
                }
            }
        }
    }
    #pragma unroll
    for (int m = 0; m < 2; ++m)
        #pragma unroll
        for (int r = 0; r < 4; ++r)
            #pragma unroll
            for (int cc = 0; cc < 2; ++cc)
                #pragma unroll
                for (int off = 1; off < 16; off <<= 1)
                    ps[m][r][cc] += __shfl_xor(ps[m][r][cc], off, 64);
    if (cn == 0) {
        #pragma unroll
        for (int m = 0; m < 2; ++m)
            #pragma unroll
            for (int r = 0; r < 4; ++r) {
                int pr = (m << 4) + (g << 2) + r;
                if (pr < MT) {
                    red[wid][pr][0] = ps[m][r][0];
                    red[wid][pr][1] = ps[m][r][1];
                }
            }
    }
    __syncthreads();
    if (t < MT * 2) {
        int pr = t >> 1, c = t & 1;
        float v = b2[c];
        #pragma unroll
        for (int w = 0; w < 8; ++w) v += red[w][pr][c];
        sflow[pr][c] = srem[pr][c] + v;   // remainder_flow
    }
    __syncthreads();

    // ---- Phase 4: bilinear warp loss, 16 lanes per patch (xj = lt) ----
    {
        const int gi = t >> 4;        // 0..31
        const int lt = t & 15;
        if (gi < MT) {
            const int pi = gi;
            const float rfy = sflow[pi][0], rfx = sflow[pi][1];
            const int xj = lt;

            float x  = (float)xj + rfx;
            int   x0 = min(max((int)floorf(x), 0), PSZ - 1);
            int   x1 = min(x0 + 1, PSZ - 1);
            float wx = fminf(fmaxf(x - (float)x0, 0.f), 1.f);
            int   c0 = x0 * 3, c1 = x1 * 3;

            float lsum = 0.f;
            #pragma unroll 4
            for (int yi = 0; yi < PSZ; ++yi) {
                float y  = (float)yi + rfy;
                int   y0 = min(max((int)floorf(y), 0), PSZ - 1);
                int   y1 = min(y0 + 1, PSZ - 1);
                float wy = fminf(fmaxf(y - (float)y0, 0.f), 1.f);
                int r0 = 768 + y0 * 48, r1 = 768 + y1 * 48;
                int ep = yi * 48 + xj * 3;
                #pragma unroll
                for (int cc = 0; cc < 3; ++cc) {
                    float v00 = bf2f(feat[fidx(pi, r0 + c0 + cc)]);
                    float v01 = bf2f(feat[fidx(pi, r0 + c1 + cc)]);
                    float v10 = bf2f(feat[fidx(pi, r1 + c0 + cc)]);
                    float v11 = bf2f(feat[fidx(pi, r1 + c1 + cc)]);
                    float a = v00 + wx * (v01 - v00);
                    float b = v10 + wx * (v11 - v10);
                    float warped = a + wy * (b - a);
                    float d = warped - bf2f(feat[fidx(pi, ep + cc)]);
                    lsum = fmaf(d, d, lsum);
                }
            }
            #pragma unroll
            for (int off = 1; off < 16; off <<= 1)
                lsum += __shfl_xor(lsum, off, 64);

            if (lt == 0) {
                int n = n0 + pi;
                out[(size_t)n * 3 + 0] = (float)sip[pi][0] + rfy;
                out[(size_t)n * 3 + 1] = (float)sip[pi][1] + rfx;
                out[(size_t)n * 3 + 2] = lsum * (1.f / 768.f);
            }
        }
    }
}

extern "C" void kernel_launch(void* const* d_in, const int* in_sizes, int n_in,
                              void* d_out, int out_size, void* d_ws, size_t ws_size,
                              hipStream_t stream) {
    const float* img1  = (const float*)d_in[0];
    const float* img2  = (const float*)d_in[1];
    const float* prior = (const float*)d_in[2];
    const float* w1    = (const float*)d_in[3];
    const float* b1    = (const float*)d_in[4];
    const float* w2    = (const float*)d_in[5];
    const float* b2    = (const float*)d_in[6];
    float* out = (float*)d_out;
    ushort* w1p = (ushort*)d_ws;            // 1536*512*2 B = 1.57 MB

    pack_w1_kernel<<<dim3((1536 * HID) / 256), dim3(256), 0, stream>>>(w1, w1p);

    dim3 grid(NPATCH / MT);                 // 2646 blocks, exact
    dim3 block(NTH);
    lfe_mfma_kernel<<<grid, block, 0, stream>>>(img1, img2, prior, w1, b1, w2, b2, w1p, out);
}

// Round 12
// 331.268 us; speedup vs baseline: 1.7721x; 1.4429x over previous
//
#include <hip/hip_runtime.h>

// Problem constants (fixed by setup_inputs)
#define BQ   16
#define HH   512
#define WW   512
#define CC   3
#define PSZ  16
#define STR  8
#define PYN  63
#define PXN  63
#define NPATCH (BQ * PYN * PXN)   // 63504
#define HID  512
#define MT   48                   // patches per block; 63504/48 = 1323 exactly
#define NTH  512                  // 8 waves; each: 3 M-tiles x 64 N-cols
#define KH   24                   // K-steps per half (768 feats = one patch image)

typedef __attribute__((ext_vector_type(8))) short  short8;
typedef __attribute__((ext_vector_type(4))) float  f32x4;

__device__ __forceinline__ ushort f2bf(float f) {
    unsigned u = __float_as_uint(f);
    u = (u + 0x7fffu + ((u >> 16) & 1u)) >> 16;   // RNE
    return (ushort)u;
}
__device__ __forceinline__ unsigned pk2(float a, float b) {
    return (unsigned)f2bf(a) | ((unsigned)f2bf(b) << 16);
}

// Pack w1[0:1536][0:512] -> bf16, lane-linear fragment order:
// idx = ((s*32 + ntg)*64 + g*16 + cn)*8 + kk   (s=k>>5, g=(k>>3)&3, kk=k&7, ntg=n>>4, cn=n&15)
__global__ void pack_w1_kernel(const float* __restrict__ w1, ushort* __restrict__ w1p) {
    int e = blockIdx.x * 256 + threadIdx.x;   // 0 .. 1536*512-1
    int k = e >> 9;
    int n = e & 511;
    int idx = ((k >> 5) << 14) + ((n >> 4) << 9) + (((k >> 3) & 3) << 7) + ((n & 15) << 3) + (k & 7);
    w1p[idx] = f2bf(w1[e]);
}

// ================= Kernel A: GEMM + flow (K-tiled, loss split out) =================
__global__ __launch_bounds__(NTH, 4)   // VGPR cap 128; 2 blocks/CU via LDS (~78 KB)
void lfe_gemm_kernel(const float* __restrict__ img1,
                     const float* __restrict__ img2,
                     const float* __restrict__ prior,
                     const float* __restrict__ w1,
                     const float* __restrict__ b1,
                     const float* __restrict__ w2,
                     const float* __restrict__ b2,
                     const ushort* __restrict__ w1p,
                     float* __restrict__ out)
{
    // feat: one K-half of A-fragments. (patch pi, local k) at
    //   ((m*KH + s)*4 + g)*128 + (pi&15)*8 + kk   (m=pi>>4, s=k>>5, g=(k>>3)&3, kk=k&7)
    __shared__ ushort feat[3 * KH * 512];     // 73728 B
    __shared__ float  red[8][MT][2];          // 3072 B
    __shared__ float  srem[MT][2];
    __shared__ int    sip[MT][2];
    __shared__ int    sbase1[MT];
    __shared__ int    sbase2[MT];

    const int t    = threadIdx.x;
    const int wid  = t >> 6;         // 0..7
    const int lane = t & 63;
    const int n0   = blockIdx.x * MT;

    // ---- Hoisted B prefetch (independent of LDS; hides under phase 0/1) ----
    const int ntb = wid << 2;                      // first ntg of this wave's 64-col slice
    const ushort* bbase = w1p + ((size_t)lane << 3);
    short8 B0[4], B1[4];
    #define LOADB(Bv, s_) {                                           \
        const ushort* p_ = bbase + ((size_t)(((s_) << 5) + ntb) << 9);\
        Bv[0] = *(const short8*)(p_);                                 \
        Bv[1] = *(const short8*)(p_ + 512);                           \
        Bv[2] = *(const short8*)(p_ + 1024);                          \
        Bv[3] = *(const short8*)(p_ + 1536);                          \
    }
    LOADB(B0, 0);
    LOADB(B1, 1);

    // ---- Phase 0: prior -> int/remainder + patch base offsets ----
    if (t < MT) {
        int n = n0 + t;
        float py_ = prior[(size_t)n * 2 + 0];
        float px_ = prior[(size_t)n * 2 + 1];
        int ipy = (int)rintf(py_);   // RNE == jnp.round
        int ipx = (int)rintf(px_);
        sip[t][0] = ipy; sip[t][1] = ipx;
        srem[t][0] = py_ - (float)ipy;
        srem[t][1] = px_ - (float)ipx;
        int b  = n / (PYN * PXN);
        int r  = n % (PYN * PXN);
        int py = r / PXN, px = r % PXN;
        int by = py * STR, bx = px * STR;
        int sy = min(max(by + ipy, 0), HH - PSZ);
        int sx = min(max(bx + ipx, 0), WW - PSZ);
        sbase1[t] = ((b * HH + by) * WW + bx) * CC;
        sbase2[t] = ((b * HH + sy) * WW + sx) * CC;
    }
    __syncthreads();

    const int plo = lane >> 2;   // patch-low 0..15
    const int kk2 = lane & 3;    // pair index
    // stage one K-half: 288 combos (m,s,g) / 8 waves = 36 per wave
    #define STAGE(tile) {                                                      \
        _Pragma("unroll 4")                                                    \
        for (int i = 0; i < 36; ++i) {                                         \
            int c = (i << 3) + wid;          /* 0..287, wave-uniform */        \
            int m = c / 96;                                                    \
            int r = c - m * 96;                                                \
            int s = r >> 2, g = r & 3;                                         \
            int pi = (m << 4) + plo;                                           \
            int e  = (s << 5) + (g << 3) + (kk2 << 1);   /* 0..766 even */     \
            const float* src = (tile) ? img2 + sbase2[pi] : img1 + sbase1[pi]; \
            int yi  = e / 48;            /* 8-runs never straddle 48-bounds */ \
            int off = e - yi * 48;                                             \
            const float* g8 = src + yi * (WW * CC) + off;                      \
            int idx = (((m * KH + s) << 2) + g) << 7;                          \
            idx += (plo << 3) + (kk2 << 1);                                    \
            *(unsigned*)(&feat[idx]) = pk2(g8[0], g8[1]);                      \
        }                                                                      \
    }

    STAGE(0);
    __syncthreads();

    // ---- GEMM ----
    const int cn = lane & 15;
    const int g  = lane >> 4;

    f32x4 acc[3][4];
    #pragma unroll
    for (int m = 0; m < 3; ++m)
        #pragma unroll
        for (int nt = 0; nt < 4; ++nt) acc[m][nt] = f32x4{0.f, 0.f, 0.f, 0.f};

    #define AIDX(m, s_) ((((m) * KH + (s_)) << 9) + ((g) << 7) + ((cn) << 3))
    #define KSTEP(s_, Bv) {                                                    \
        short8 A0 = *(const short8*)(feat + AIDX(0, s_));                      \
        short8 A1 = *(const short8*)(feat + AIDX(1, s_));                      \
        short8 A2 = *(const short8*)(feat + AIDX(2, s_));                      \
        _Pragma("unroll")                                                      \
        for (int nt = 0; nt < 4; ++nt) {                                       \
            acc[0][nt] = __builtin_amdgcn_mfma_f32_16x16x32_bf16(A0, Bv[nt], acc[0][nt], 0, 0, 0); \
            acc[1][nt] = __builtin_amdgcn_mfma_f32_16x16x32_bf16(A1, Bv[nt], acc[1][nt], 0, 0, 0); \
            acc[2][nt] = __builtin_amdgcn_mfma_f32_16x16x32_bf16(A2, Bv[nt], acc[2][nt], 0, 0, 0); \
        }                                                                      \
    }

    // K-half 1: slabs 0..23 ; entering iter s: B0=slab s, B1=slab s+1
    for (int s = 0; s < KH; s += 2) {
        KSTEP(s, B0);
        LOADB(B0, s + 2);          // at s=22 -> slab 24 (first of half 2)
        KSTEP(s + 1, B1);
        LOADB(B1, s + 3);          // at s=22 -> slab 25
    }
    __syncthreads();               // all p1 ds_reads done
    STAGE(1);                      // overwrite LDS with p2
    __syncthreads();
    // K-half 2: slabs 24..47 ; invariant holds (B0=24, B1=25)
    for (int s = 0; s < KH; s += 2) {
        KSTEP(s, B0);
        int sa = min(26 + s, 47);  // clamped dummy at tail
        LOADB(B0, sa);
        KSTEP(s + 1, B1);
        int sb = min(27 + s, 47);
        LOADB(B1, sb);
    }
    #undef LOADB
    #undef KSTEP
    #undef AIDX
    #undef STAGE

    // ---- Epilogue: rem features + b1, ReLU, fold w2, reduce over cn, write flow ----
    float ps[3][4][2];
    #pragma unroll
    for (int m = 0; m < 3; ++m)
        #pragma unroll
        for (int r = 0; r < 4; ++r) { ps[m][r][0] = 0.f; ps[m][r][1] = 0.f; }

    #pragma unroll
    for (int nt = 0; nt < 4; ++nt) {
        int j = (wid << 6) + (nt << 4) + cn;
        float w1a = w1[(size_t)1536 * HID + j];
        float w1b = w1[(size_t)1537 * HID + j];
        float bb  = b1[j];
        float w20 = w2[(size_t)j * 2 + 0];
        float w21 = w2[(size_t)j * 2 + 1];
        #pragma unroll
        for (int m = 0; m < 3; ++m) {
            #pragma unroll
            for (int r = 0; r < 4; ++r) {
                int pr = (m << 4) + (g << 2) + r;   // C/D: row = (lane>>4)*4 + reg
                float h = acc[m][nt][r] + bb + srem[pr][0] * w1a + srem[pr][1] * w1b;
                h = fmaxf(h, 0.f);
                ps[m][r][0] = fmaf(h, w20, ps[m][r][0]);
                ps[m][r][1] = fmaf(h, w21, ps[m][r][1]);
            }
        }
    }
    #pragma unroll
    for (int m = 0; m < 3; ++m)
        #pragma unroll
        for (int r = 0; r < 4; ++r)
            #pragma unroll
            for (int cc = 0; cc < 2; ++cc)
                #pragma unroll
                for (int off = 1; off < 16; off <<= 1)
                    ps[m][r][cc] += __shfl_xor(ps[m][r][cc], off, 64);
    if (cn == 0) {
        #pragma unroll
        for (int m = 0; m < 3; ++m)
            #pragma unroll
            for (int r = 0; r < 4; ++r) {
                int pr = (m << 4) + (g << 2) + r;
                red[wid][pr][0] = ps[m][r][0];
                red[wid][pr][1] = ps[m][r][1];
            }
    }
    __syncthreads();
    if (t < MT * 2) {
        int pr = t >> 1, c = t & 1;
        float v = b2[c];
        #pragma unroll
        for (int w = 0; w < 8; ++w) v += red[w][pr][c];
        float rf = srem[pr][c] + v;                       // remainder_flow
        out[(size_t)(n0 + pr) * 3 + c] = (float)sip[pr][c] + rf;
    }
}

// ================= Kernel B: bilinear warp loss from fp32 images =================
__global__ __launch_bounds__(256)
void lfe_loss_kernel(const float* __restrict__ img1,
                     const float* __restrict__ img2,
                     const float* __restrict__ prior,
                     float* __restrict__ out)
{
    const int t  = threadIdx.x;
    const int gi = t >> 4;           // patch within block (0..15)
    const int xj = t & 15;           // x position
    const int n  = blockIdx.x * 16 + gi;

    // recompute patch geometry (matches kernel A)
    float py_ = prior[(size_t)n * 2 + 0];
    float px_ = prior[(size_t)n * 2 + 1];
    int ipy = (int)rintf(py_);
    int ipx = (int)rintf(px_);
    int b  = n / (PYN * PXN);
    int r  = n % (PYN * PXN);
    int py = r / PXN, px = r % PXN;
    int by = py * STR, bx = px * STR;
    int sy = min(max(by + ipy, 0), HH - PSZ);
    int sx = min(max(bx + ipx, 0), WW - PSZ);
    const float* p1 = img1 + (size_t)((b * HH + by) * WW + bx) * CC;
    const float* p2 = img2 + (size_t)((b * HH + sy) * WW + sx) * CC;

    // remainder_flow from kernel A's flow output
    float rfy = out[(size_t)n * 3 + 0] - (float)ipy;
    float rfx = out[(size_t)n * 3 + 1] - (float)ipx;

    float x  = (float)xj + rfx;
    int   x0 = min(max((int)floorf(x), 0), PSZ - 1);
    int   x1 = min(x0 + 1, PSZ - 1);
    float wx = fminf(fmaxf(x - (float)x0, 0.f), 1.f);
    int   c0 = x0 * 3, c1 = x1 * 3;

    float lsum = 0.f;
    #pragma unroll 4
    for (int yi = 0; yi < PSZ; ++yi) {
        float y  = (float)yi + rfy;
        int   y0 = min(max((int)floorf(y), 0), PSZ - 1);
        int   y1 = min(y0 + 1, PSZ - 1);
        float wy = fminf(fmaxf(y - (float)y0, 0.f), 1.f);
        const float* r0p = p2 + (size_t)y0 * (WW * CC);
        const float* r1p = p2 + (size_t)y1 * (WW * CC);
        const float* p1r = p1 + (size_t)yi * (WW * CC) + xj * 3;
        #pragma unroll
        for (int cc = 0; cc < 3; ++cc) {
            float v00 = r0p[c0 + cc];
            float v01 = r0p[c1 + cc];
            float v10 = r1p[c0 + cc];
            float v11 = r1p[c1 + cc];
            float a = v00 + wx * (v01 - v00);
            float bl = v10 + wx * (v11 - v10);
            float warped = a + wy * (bl - a);
            float d = warped - p1r[cc];
            lsum = fmaf(d, d, lsum);
        }
    }
    #pragma unroll
    for (int off = 1; off < 16; off <<= 1)
        lsum += __shfl_xor(lsum, off, 64);

    if (xj == 0)
        out[(size_t)n * 3 + 2] = lsum * (1.f / 768.f);
}

extern "C" void kernel_launch(void* const* d_in, const int* in_sizes, int n_in,
                              void* d_out, int out_size, void* d_ws, size_t ws_size,
                              hipStream_t stream) {
    const float* img1  = (const float*)d_in[0];
    const float* img2  = (const float*)d_in[1];
    const float* prior = (const float*)d_in[2];
    const float* w1    = (const float*)d_in[3];
    const float* b1    = (const float*)d_in[4];
    const float* w2    = (const float*)d_in[5];
    const float* b2    = (const float*)d_in[6];
    float* out = (float*)d_out;
    ushort* w1p = (ushort*)d_ws;            // 1536*512*2 B = 1.57 MB

    pack_w1_kernel<<<dim3((1536 * HID) / 256), dim3(256), 0, stream>>>(w1, w1p);

    lfe_gemm_kernel<<<dim3(NPATCH / MT), dim3(NTH), 0, stream>>>(
        img1, img2, prior, w1, b1, w2, b2, w1p, out);

    lfe_loss_kernel<<<dim3(NPATCH / 16), dim3(256), 0, stream>>>(
        img1, img2, prior, out);
}